// Round 1
// baseline (258.119 us; speedup 1.0000x reference)
//
#include <hip/hip_runtime.h>
#include <hip/hip_fp16.h>

#define NW 18
#define NSTATE (1u << NW)                      // 262144 per batch
#define NBATCH 32
#define TOTAL (NBATCH * (size_t)NSTATE)        // 8388608 elements

struct Masks { unsigned m[18]; };

// complex 2x2 butterfly: (a,b) <- (g0.(a,b), g1.(a,b)), g = (m.re, m.im, m'.re, m'.im)
__device__ __forceinline__ void bfly(float2& a, float2& b, const float4 g0, const float4 g1) {
    float ax = a.x, ay = a.y, bx = b.x, by = b.y;
    float nax = g0.x*ax - g0.y*ay + g0.z*bx - g0.w*by;
    float nay = g0.x*ay + g0.y*ax + g0.z*by + g0.w*bx;
    float nbx = g1.x*ax - g1.y*ay + g1.z*bx - g1.w*by;
    float nby = g1.x*ay + g1.y*ax + g1.z*by + g1.w*bx;
    a.x = nax; a.y = nay; b.x = nbx; b.y = nby;
}

__device__ __forceinline__ int swz(int n) { return n ^ ((n >> 5) & 31); }

// ---- gate matrices from params + zero the norm accumulators -------------------
__global__ void prep(const float* __restrict__ params, float4* __restrict__ Utab,
                     float* __restrict__ norms) {
    int i = threadIdx.x;
    if (i < 36) {
        float phi = params[i*3+0], th = params[i*3+1], om = params[i*3+2];
        float ch = cosf(th*0.5f), sh = sinf(th*0.5f);
        float a0 = -0.5f*(phi+om);
        float a1 =  0.5f*(phi-om);
        float c0 = cosf(a0), s0 = sinf(a0);
        float c1 = cosf(a1), s1 = sinf(a1);
        // m00 = e^{i a0} ch ; m01 = -e^{i a1} sh ; m10 = e^{-i a1} sh ; m11 = e^{-i a0} ch
        Utab[i*2+0] = make_float4(c0*ch,  s0*ch, -c1*sh, -s1*sh);
        Utab[i*2+1] = make_float4(c1*sh, -s1*sh,  c0*ch, -s0*ch);
    }
    if (i >= 64 && i < 96) norms[i-64] = 0.f;
}

// ---- per-batch sum of squares -------------------------------------------------
__global__ __launch_bounds__(256) void normk(const float* __restrict__ x,
                                             float* __restrict__ norms) {
    int t = threadIdx.x;
    size_t base = (size_t)blockIdx.x * 4096;
    int batch = (int)(base >> NW);
    const float4* p = (const float4*)(x + base);
    float s = 0.f;
#pragma unroll
    for (int j = 0; j < 4; j++) {
        float4 q = p[t + j*256];
        s += q.x*q.x + q.y*q.y + q.z*q.z + q.w*q.w;
    }
#pragma unroll
    for (int m = 32; m >= 1; m >>= 1) s += __shfl_xor(s, m, 64);
    __shared__ float ws[4];
    if ((t & 63) == 0) ws[t >> 6] = s;
    __syncthreads();
    if (t == 0) atomicAdd(&norms[batch], ws[0]+ws[1]+ws[2]+ws[3]);
}

// ---- pass A: butterflies on bits 0..12 within contiguous 8192 blocks ----------
template<int SRC_F32>
__global__ __launch_bounds__(256) void passA(const void* __restrict__ src,
                                             __half2* __restrict__ dst,
                                             const float4* __restrict__ Utab,
                                             const float* __restrict__ norms,
                                             int layer) {
    __shared__ __half2 sm[8192];   // 32 KB
    const int t = threadIdx.x;
    const size_t base = (size_t)blockIdx.x * 8192;
    float2 v[32];

    if (SRC_F32) {
        const float* xs = (const float*)src + base + (size_t)t * 32;
        float sc = 1.0f / sqrtf(norms[base >> NW]);
#pragma unroll
        for (int j = 0; j < 8; j++) {
            float4 q = ((const float4*)xs)[j];
            v[j*4+0] = make_float2(q.x*sc, 0.f);
            v[j*4+1] = make_float2(q.y*sc, 0.f);
            v[j*4+2] = make_float2(q.z*sc, 0.f);
            v[j*4+3] = make_float2(q.w*sc, 0.f);
        }
    } else {
        const __half2* xs = (const __half2*)src + base + (size_t)t * 32;
#pragma unroll
        for (int j = 0; j < 8; j++) {
            float4 q = ((const float4*)xs)[j];
            const __half2* h = (const __half2*)&q;
            v[j*4+0] = __half22float2(h[0]);
            v[j*4+1] = __half22float2(h[1]);
            v[j*4+2] = __half22float2(h[2]);
            v[j*4+3] = __half22float2(h[3]);
        }
    }

    const float4* Ut = Utab + (size_t)layer * 36;   // 18 gates * 2 float4

    // stages on bits 0..4 (wire 17-b); element k has bits 0..4 of local index
#pragma unroll
    for (int b = 0; b < 5; b++) {
        float4 g0 = Ut[(17-b)*2+0], g1 = Ut[(17-b)*2+1];
#pragma unroll
        for (int k = 0; k < 32; k++)
            if (!(k & (1 << b))) bfly(v[k], v[k | (1 << b)], g0, g1);
    }

    // exchange 1: tile1 n = t*32+k  ->  tile2 n = (t&31) | k<<5 | (t>>5)<<10
#pragma unroll
    for (int k = 0; k < 32; k++) {
        int n = t*32 + k;
        sm[swz(n)] = __floats2half2_rn(v[k].x, v[k].y);
    }
    __syncthreads();
#pragma unroll
    for (int k = 0; k < 32; k++) {
        int n = (t & 31) | (k << 5) | ((t >> 5) << 10);
        v[k] = __half22float2(sm[swz(n)]);
    }

    // stages on bits 5..9  (k bit b-5)
#pragma unroll
    for (int b = 5; b < 10; b++) {
        float4 g0 = Ut[(17-b)*2+0], g1 = Ut[(17-b)*2+1];
        int pb = 1 << (b - 5);
#pragma unroll
        for (int k = 0; k < 32; k++)
            if (!(k & pb)) bfly(v[k], v[k | pb], g0, g1);
    }

    // exchange 2: write back tile2 slots (same slots we read: no sync needed before),
    // then read tile3 n = (t&31) | (t>>5)<<5 | (k&3)<<8 | (k>>2)<<10
#pragma unroll
    for (int k = 0; k < 32; k++) {
        int n = (t & 31) | (k << 5) | ((t >> 5) << 10);
        sm[swz(n)] = __floats2half2_rn(v[k].x, v[k].y);
    }
    __syncthreads();
#pragma unroll
    for (int k = 0; k < 32; k++) {
        int n = (t & 31) | ((t >> 5) << 5) | ((k & 3) << 8) | ((k >> 2) << 10);
        v[k] = __half22float2(sm[swz(n)]);
    }

    // stages on bits 10..12 (k bit b-8)
#pragma unroll
    for (int b = 10; b < 13; b++) {
        float4 g0 = Ut[(17-b)*2+0], g1 = Ut[(17-b)*2+1];
        int pb = 1 << (b - 8);
#pragma unroll
        for (int k = 0; k < 32; k++)
            if (!(k & pb)) bfly(v[k], v[k | pb], g0, g1);
    }

    // store (tile3 layout: lane-contiguous, coalesced)
#pragma unroll
    for (int k = 0; k < 32; k++) {
        int n = (t & 31) | ((t >> 5) << 5) | ((k & 3) << 8) | ((k >> 2) << 10);
        dst[base + n] = __floats2half2_rn(v[k].x, v[k].y);
    }
}

// ---- pass B: butterflies on bits 13..17, then CNOT-chain scatter --------------
// LAST=1: write |amp| as f32 to out; else half2 state.
template<int LAST>
__global__ __launch_bounds__(256) void passB(const __half2* __restrict__ src,
                                             void* __restrict__ dst,
                                             const float4* __restrict__ Utab,
                                             int layer, Masks mk) {
    const unsigned tid = blockIdx.x * 256 + threadIdx.x;   // 0 .. 2^18-1
    const unsigned batch = tid >> 13;
    const unsigned lo = tid & 8191u;
    const size_t bb = (size_t)batch << NW;
    float2 v[32];
#pragma unroll
    for (int s = 0; s < 32; s++)
        v[s] = __half22float2(src[bb + ((unsigned)s << 13) + lo]);

    const float4* Ut = Utab + (size_t)layer * 36;
#pragma unroll
    for (int b = 13; b < 18; b++) {
        float4 g0 = Ut[(17-b)*2+0], g1 = Ut[(17-b)*2+1];
        int pb = 1 << (b - 13);
#pragma unroll
        for (int s = 0; s < 32; s++)
            if (!(s & pb)) bfly(v[s], v[s | pb], g0, g1);
    }

    // scatter through the GF(2)-linear CNOT-chain map: F(y) = xor of column masks
    unsigned f = 0;
#pragma unroll
    for (int k = 0; k < 13; k++) f ^= ((lo >> k) & 1u) ? mk.m[k] : 0u;

#pragma unroll
    for (int s = 0; s < 32; s++) {
        unsigned fs = f;
        if (s & 1)  fs ^= mk.m[13];
        if (s & 2)  fs ^= mk.m[14];
        if (s & 4)  fs ^= mk.m[15];
        if (s & 8)  fs ^= mk.m[16];
        if (s & 16) fs ^= mk.m[17];
        if (LAST) {
            ((float*)dst)[bb + fs] = sqrtf(v[s].x*v[s].x + v[s].y*v[s].y);
        } else {
            ((__half2*)dst)[bb + fs] = __floats2half2_rn(v[s].x, v[s].y);
        }
    }
}

// ---- host: CNOT chain as an 18x18 GF(2) matrix -> column masks ----------------
static void chain_masks(int l, Masks* mk) {
    unsigned rows[18];
    for (int j = 0; j < 18; j++) rows[j] = 1u << j;      // new bit j as fn of old bits
    for (int i = 0; i < 18; i++) {
        int cw = (i + l) % 18, tw = (i + l + 1) % 18;    // wires
        rows[17 - tw] ^= rows[17 - cw];                  // bit_t ^= bit_c
    }
    for (int k = 0; k < 18; k++) {                       // transpose into column masks
        unsigned cm = 0;
        for (int j = 0; j < 18; j++) cm |= ((rows[j] >> k) & 1u) << j;
        mk->m[k] = cm;
    }
}

extern "C" void kernel_launch(void* const* d_in, const int* in_sizes, int n_in,
                              void* d_out, int out_size, void* d_ws, size_t ws_size,
                              hipStream_t stream) {
    const float* x      = (const float*)d_in[0];
    const float* params = (const float*)d_in[1];

    char* ws = (char*)d_ws;
    __half2* bufA = (__half2*)ws;                        // 32 MB
    __half2* bufB = (__half2*)(ws + TOTAL * 4);          // 32 MB
    float4*  Utab = (float4*)(ws + TOTAL * 8);           // 72 * 16 B
    float*   norms = (float*)(ws + TOTAL * 8 + 4096);    // 32 f32

    Masks mk1, mk2;
    chain_masks(0, &mk1);
    chain_masks(1, &mk2);

    prep<<<1, 96, 0, stream>>>(params, Utab, norms);
    normk<<<2048, 256, 0, stream>>>(x, norms);
    passA<1><<<1024, 256, 0, stream>>>((const void*)x, bufA, Utab, norms, 0);
    passB<0><<<1024, 256, 0, stream>>>(bufA, (void*)bufB, Utab, 0, mk1);
    passA<0><<<1024, 256, 0, stream>>>((const void*)bufB, bufB, Utab, norms, 1);
    passB<1><<<1024, 256, 0, stream>>>(bufB, d_out, Utab, 1, mk2);
}